// Round 3
// baseline (367.324 us; speedup 1.0000x reference)
//
#include <hip/hip_runtime.h>

#define EDIM 10
#define TDIM 50
#define BATCH 65536
#define WPAD 12                    // weight row padded to 12 floats = 48B (16B-aligned rows)
#define WTOT (63 * WPAD)           // 60 matrix rows + 3 bias rows = 756 floats (3KB)

// Collapsed-weight global, LDS-friendly padded layout (written by collapse_weights):
//   row r = g*20 + k        : A_g[k][0..9]  (A_g = Wi_g @ Ws_g)      g: 0=r,1=z,2=h
//   row r = g*20 + 10 + k   : B_g[k][0..9]  (B_g = Wh_g @ Ws_g)
//   row r = 60 + g          : bias_g[0..9]  (bias_g = bi_g @ Ws_g + bs_g)
// float index = r*WPAD + j, j=10,11 are zero pads.
__device__ float g_cwp[WTOT];

#define WROWA(g, k) (((g) * 20 + (k)) * WPAD)
#define WROWB(g, k) (((g) * 20 + 10 + (k)) * WPAD)
#define WBIAS(g)    ((60 + (g)) * WPAD)

__device__ __forceinline__ float fast_sigmoid(float x) {
    float e = __expf(-x);
    return __builtin_amdgcn_rcpf(1.0f + e);
}
__device__ __forceinline__ float fast_tanh(float x) {
    float e = __expf(2.0f * x);
    return 1.0f - 2.0f * __builtin_amdgcn_rcpf(e + 1.0f);
}

// dst[0..9] += s * row[0..9], row 16B-aligned: ds_read_b128 + b128 + b64 broadcast
#define MV_ROW(dst, s, rowptr) do {                                          \
    const float* rp_ = (rowptr);                                             \
    float4 w0_ = *(const float4*)(rp_);                                      \
    float4 w1_ = *(const float4*)(rp_ + 4);                                  \
    float2 w2_ = *(const float2*)(rp_ + 8);                                  \
    dst[0] = fmaf((s), w0_.x, dst[0]); dst[1] = fmaf((s), w0_.y, dst[1]);    \
    dst[2] = fmaf((s), w0_.z, dst[2]); dst[3] = fmaf((s), w0_.w, dst[3]);    \
    dst[4] = fmaf((s), w1_.x, dst[4]); dst[5] = fmaf((s), w1_.y, dst[5]);    \
    dst[6] = fmaf((s), w1_.z, dst[6]); dst[7] = fmaf((s), w1_.w, dst[7]);    \
    dst[8] = fmaf((s), w2_.x, dst[8]); dst[9] = fmaf((s), w2_.y, dst[9]);    \
} while (0)

#define LD_ROW(dst, rowptr) do {                                             \
    const float* rp_ = (rowptr);                                             \
    float4 w0_ = *(const float4*)(rp_);                                      \
    float4 w1_ = *(const float4*)(rp_ + 4);                                  \
    float2 w2_ = *(const float2*)(rp_ + 8);                                  \
    dst[0] = w0_.x; dst[1] = w0_.y; dst[2] = w0_.z; dst[3] = w0_.w;          \
    dst[4] = w1_.x; dst[5] = w1_.y; dst[6] = w1_.z; dst[7] = w1_.w;          \
    dst[8] = w2_.x; dst[9] = w2_.y;                                          \
} while (0)

__global__ void collapse_weights(
    const float* __restrict__ Wi_r, const float* __restrict__ bi_r,
    const float* __restrict__ Wh_r, const float* __restrict__ Ws_r, const float* __restrict__ bs_r,
    const float* __restrict__ Wi_z, const float* __restrict__ bi_z,
    const float* __restrict__ Wh_z, const float* __restrict__ Ws_z, const float* __restrict__ bs_z,
    const float* __restrict__ Wi_h, const float* __restrict__ bi_h,
    const float* __restrict__ Wh_h, const float* __restrict__ Wt_h, const float* __restrict__ bt_h)
{
    for (int s = threadIdx.x; s < WTOT; s += 256) {
        int r = s / WPAD, j = s % WPAD;
        float v = 0.0f;
        if (j < 10) {
            if (r < 60) {
                int g = r / 20, kind = (r % 20) / 10, k = r % 10;
                const float* Ws = (g == 0) ? Ws_r : (g == 1) ? Ws_z : Wt_h;
                const float* M  = (kind == 0)
                    ? ((g == 0) ? Wi_r : (g == 1) ? Wi_z : Wi_h)
                    : ((g == 0) ? Wh_r : (g == 1) ? Wh_z : Wh_h);
                #pragma unroll
                for (int jj = 0; jj < 10; jj++) v += M[k * 10 + jj] * Ws[jj * 10 + j];
            } else {
                int g = r - 60;
                const float* Ws = (g == 0) ? Ws_r : (g == 1) ? Ws_z : Wt_h;
                const float* bi = (g == 0) ? bi_r : (g == 1) ? bi_z : bi_h;
                const float* bs = (g == 0) ? bs_r : (g == 1) ? bs_z : bt_h;
                v = bs[j];
                #pragma unroll
                for (int jj = 0; jj < 10; jj++) v += bi[jj] * Ws[jj * 10 + j];
            }
        }
        g_cwp[s] = v;
    }
}

__global__ __launch_bounds__(256, 1) void augru_main(
    const float* __restrict__ x_all, const float* __restrict__ a_all,
    const float* __restrict__ h0,
    float* __restrict__ out)
{
    __shared__ __align__(16) float WL[WTOT];
    for (int s = threadIdx.x; s < WTOT; s += 256) WL[s] = g_cwp[s];
    __syncthreads();   // once; no barriers in the t-loop

    const int row = blockIdx.x * 256 + threadIdx.x;   // one FULL row per lane

    const float2* xp = (const float2*)(x_all + (size_t)row * (TDIM * EDIM));
    const float2* ap = (const float2*)(a_all + (size_t)row * (TDIM * EDIM));

    float h[10];
    #pragma unroll
    for (int j = 0; j < 10; j++) h[j] = h0[j];   // uniform -> scalar loads (10, once)

    float xc[10], ac[10];
    #pragma unroll
    for (int i = 0; i < 5; i++) {
        float2 v = xp[i]; xc[2 * i] = v.x; xc[2 * i + 1] = v.y;
        float2 u = ap[i]; ac[2 * i] = u.x; ac[2 * i + 1] = u.y;
    }

    // Laundered LDS offset: keeps every weight address loop-variant so LICM
    // cannot hoist 630 broadcast ds_reads into registers (no VGPR budget ->
    // would scratch-spill). Proven trick from rounds 1-2.
    int wofs = 0;

    #pragma unroll 1
    for (int t = 0; t < TDIM; t++) {
        asm volatile("" : "+v"(wofs));
        const float* w = (const float*)WL + wofs;

        // branchless 1-step-lookahead prefetch (clamped); ~2400cy of compute
        // below covers LLC/HBM latency on these strided per-row streams.
        int tn = (t < TDIM - 1) ? (t + 1) : t;
        float xn[10], an[10];
        #pragma unroll
        for (int i = 0; i < 5; i++) {
            float2 v = xp[tn * 5 + i]; xn[2 * i] = v.x; xn[2 * i + 1] = v.y;
            float2 u = ap[tn * 5 + i]; an[2 * i] = u.x; an[2 * i + 1] = u.y;
        }

        float ur[10], uz[10], uh[10];
        LD_ROW(ur, w + WBIAS(0));
        LD_ROW(uz, w + WBIAS(1));
        LD_ROW(uh, w + WBIAS(2));

        #pragma unroll
        for (int k = 0; k < 10; k++) MV_ROW(ur, xc[k], w + WROWA(0, k));   // x @ A_r
        #pragma unroll
        for (int k = 0; k < 10; k++) MV_ROW(uz, xc[k], w + WROWA(1, k));   // x @ A_z
        #pragma unroll
        for (int k = 0; k < 10; k++) MV_ROW(ur, h[k],  w + WROWB(0, k));   // h @ B_r
        #pragma unroll
        for (int k = 0; k < 10; k++) MV_ROW(uz, h[k],  w + WROWB(1, k));   // h @ B_z
        // x @ A_h here: independent FMA stream covering the z-sigmoid latency
        #pragma unroll
        for (int k = 0; k < 10; k++) MV_ROW(uh, xc[k], w + WROWA(2, k));   // x @ A_h

        float hz[10];
        #pragma unroll
        for (int j = 0; j < 10; j++) hz[j] = h[j] * fast_sigmoid(uz[j]);

        #pragma unroll
        for (int k = 0; k < 10; k++) MV_ROW(uh, hz[k], w + WROWB(2, k));   // (h*z) @ B_h

        #pragma unroll
        for (int j = 0; j < 10; j++) {
            float r  = fast_sigmoid(ur[j]);
            float hc = fast_tanh(uh[j]);
            float Ra = ac[j] * r;
            h[j] = fmaf(Ra, hc - h[j], h[j]);
        }

        #pragma unroll
        for (int j = 0; j < 10; j++) { xc[j] = xn[j]; ac[j] = an[j]; }
    }

    // lane L writes bytes [40L, 40L+40) -> wave store fully contiguous
    float2* orow = (float2*)(out + (size_t)row * EDIM);
    #pragma unroll
    for (int i = 0; i < 5; i++) orow[i] = make_float2(h[2 * i], h[2 * i + 1]);
}

extern "C" void kernel_launch(void* const* d_in, const int* in_sizes, int n_in,
                              void* d_out, int out_size, void* d_ws, size_t ws_size,
                              hipStream_t stream) {
    collapse_weights<<<1, 256, 0, stream>>>(
        (const float*)d_in[3],  (const float*)d_in[4],  (const float*)d_in[5],
        (const float*)d_in[6],  (const float*)d_in[7],
        (const float*)d_in[8],  (const float*)d_in[9],  (const float*)d_in[10],
        (const float*)d_in[11], (const float*)d_in[12],
        (const float*)d_in[13], (const float*)d_in[14], (const float*)d_in[15],
        (const float*)d_in[16], (const float*)d_in[17]);
    augru_main<<<BATCH / 256, 256, 0, stream>>>(
        (const float*)d_in[0], (const float*)d_in[1], (const float*)d_in[2],
        (float*)d_out);
}